// Round 1
// baseline (22.539 us; speedup 1.0000x reference)
//
#include <hip/hip_runtime.h>

// Rejection sampler (speculative decoding verify): B=64, S=8, V=32000.
// Inputs: target_probs (B,S+1,V) f32, draft_probs (B,S,V) f32,
//         draft_token_ids (B,S) i32, random_uniform (B,S) f32,
//         sample_uniform (B,) f32.
// Output: (B,S+1) i32.
//
// Key insight: only ONE V-row of target (and maybe draft) per batch is needed
// (the row at reject_idx). The adj normalization denominator cancels in the
// CDF-inversion count, so we work entirely in un-normalized p-space:
//   count = #{ i : cumsum(p)_i < u * sum(p) }.

constexpr int BB = 64;
constexpr int SS = 8;
constexpr int VV = 32000;
constexpr int NTH = 512;          // threads per block
constexpr int NW = NTH / 64;      // waves per block
constexpr int CHUNK = 64;         // contiguous floats per active thread
constexpr int ACTIVE = VV / CHUNK; // 500 active threads

__global__ __launch_bounds__(NTH) void rs_kernel(
    const float* __restrict__ target,  // B x (S+1) x V
    const float* __restrict__ draft,   // B x S x V
    const int*   __restrict__ ids,     // B x S
    const float* __restrict__ ru,      // B x S
    const float* __restrict__ su,      // B
    int* __restrict__ out)             // B x (S+1)
{
    const int b    = blockIdx.x;
    const int tid  = threadIdx.x;
    const int lane = tid & 63;
    const int wid  = tid >> 6;

    __shared__ int   s_rj;
    __shared__ float s_wtot[NW];
    __shared__ int   s_count;

    // --- step 1: accept/reject chain (8 gathered scalars) ---
    if (tid == 0) {
        int rj = SS;
        for (int s = 0; s < SS; ++s) {
            int   tok = ids[b * SS + s];
            float t   = target[((size_t)b * (SS + 1) + s) * VV + tok];
            float d   = draft [((size_t)b * SS       + s) * VV + tok];
            float r   = ru[b * SS + s];
            if (t / d < r) { rj = s; break; }
        }
        s_rj    = rj;
        s_count = 0;
    }
    __syncthreads();

    const int  rj    = s_rj;
    const bool bonus = (rj == SS);
    const float* __restrict__ trow = target + ((size_t)b * (SS + 1) + rj) * VV;
    const float* __restrict__ drow = draft  + ((size_t)b * SS + (bonus ? 0 : rj)) * VV;

    const float4* t4 = reinterpret_cast<const float4*>(trow) + (size_t)tid * (CHUNK / 4);
    const float4* d4 = reinterpret_cast<const float4*>(drow) + (size_t)tid * (CHUNK / 4);

    // --- pass 1: per-thread chunk sum of p ---
    float lsum = 0.f;
    if (tid < ACTIVE) {
        if (bonus) {
            #pragma unroll
            for (int k = 0; k < CHUNK / 4; ++k) {
                float4 t = t4[k];
                lsum += t.x + t.y + t.z + t.w;
            }
        } else {
            #pragma unroll
            for (int k = 0; k < CHUNK / 4; ++k) {
                float4 t = t4[k];
                float4 d = d4[k];
                lsum += fmaxf(t.x - d.x, 0.f) + fmaxf(t.y - d.y, 0.f)
                      + fmaxf(t.z - d.z, 0.f) + fmaxf(t.w - d.w, 0.f);
            }
        }
    }

    // --- wave-level inclusive scan of chunk sums ---
    float v = lsum;
    #pragma unroll
    for (int d = 1; d < 64; d <<= 1) {
        float n = __shfl_up(v, d, 64);
        if (lane >= d) v += n;
    }
    if (lane == 63) s_wtot[wid] = v;
    __syncthreads();

    float woff = 0.f, total = 0.f;
    #pragma unroll
    for (int w = 0; w < NW; ++w) {
        float wt = s_wtot[w];
        if (w < wid) woff += wt;
        total += wt;
    }
    float prev = __shfl_up(v, 1, 64);
    float excl = woff + ((lane == 0) ? 0.f : prev);   // exclusive prefix for my chunk

    const float T = su[b] * total;

    // --- pass 2: count cdf entries strictly below threshold (L2-hot re-read) ---
    int cnt = 0;
    if (tid < ACTIVE) {
        float running = excl;
        if (bonus) {
            #pragma unroll
            for (int k = 0; k < CHUNK / 4; ++k) {
                float4 t = t4[k];
                running += t.x; cnt += (running < T);
                running += t.y; cnt += (running < T);
                running += t.z; cnt += (running < T);
                running += t.w; cnt += (running < T);
            }
        } else {
            #pragma unroll
            for (int k = 0; k < CHUNK / 4; ++k) {
                float4 t = t4[k];
                float4 d = d4[k];
                float q;
                q = fmaxf(t.x - d.x, 0.f); running += q; cnt += (running < T);
                q = fmaxf(t.y - d.y, 0.f); running += q; cnt += (running < T);
                q = fmaxf(t.z - d.z, 0.f); running += q; cnt += (running < T);
                q = fmaxf(t.w - d.w, 0.f); running += q; cnt += (running < T);
            }
        }
    }

    // block reduction of count
    #pragma unroll
    for (int off = 32; off > 0; off >>= 1) cnt += __shfl_down(cnt, off, 64);
    if (lane == 0) atomicAdd(&s_count, cnt);
    __syncthreads();

    // --- outputs: 9 ints per batch ---
    if (tid <= SS) {
        int sampled = min(s_count, VV - 1);
        int val = (tid < rj) ? ids[b * SS + tid]
                             : ((tid == rj) ? sampled : -1);
        out[b * (SS + 1) + tid] = val;
    }
}

extern "C" void kernel_launch(void* const* d_in, const int* in_sizes, int n_in,
                              void* d_out, int out_size, void* d_ws, size_t ws_size,
                              hipStream_t stream) {
    const float* target = (const float*)d_in[0];
    const float* draft  = (const float*)d_in[1];
    const int*   ids    = (const int*)  d_in[2];
    const float* ru     = (const float*)d_in[3];
    const float* su     = (const float*)d_in[4];
    int* out = (int*)d_out;

    rs_kernel<<<BB, NTH, 0, stream>>>(target, draft, ids, ru, su, out);
}